// Round 4
// baseline (1416.563 us; speedup 1.0000x reference)
//
#include <hip/hip_runtime.h>

#define B_     256
#define NI_    1152
#define NO_    10
#define DO_    16
#define DI_    8
#define PAIRS_ 160          // NO_*DO_
#define SEGS_  4
#define IPS_   (NI_/SEGS_)  // 288

// iter 0: cmat = 0.1 (softmax of zeros), blog = 0.   iter>0: cmat = softmax(blog).
__global__ __launch_bounds__(256) void c_kernel(float* __restrict__ blog,
                                                float* __restrict__ cmat,
                                                int init)
{
    int i = blockIdx.x * 256 + threadIdx.x;
    if (i >= NI_) return;
    if (init) {
#pragma unroll
        for (int j = 0; j < NO_; ++j) { cmat[i * NO_ + j] = 0.1f; blog[i * NO_ + j] = 0.f; }
        return;
    }
    float r[NO_];
    float m = -1e30f;
#pragma unroll
    for (int j = 0; j < NO_; ++j) { r[j] = blog[i * NO_ + j]; m = fmaxf(m, r[j]); }
    float s = 0.f;
#pragma unroll
    for (int j = 0; j < NO_; ++j) { r[j] = __expf(r[j] - m); s += r[j]; }
    float inv = 1.f / s;
#pragma unroll
    for (int j = 0; j < NO_; ++j) cmat[i * NO_ + j] = r[j] * inv;
}

// One block per batch item b. Stages x[b] (fp32, [8,1152]) transposed into LDS as
// xL[i*8+d]; thread = (seg, pair=(j,o)) recomputes u_hat on the fly from fp32 W,
// accumulates s over its i-segment, block-reduces, squashes.
// ALL __syncthreads() at top level (uniform).
__global__ __launch_bounds__(640) void sv_kernel(const float* __restrict__ x,
                                                 const float* __restrict__ W,
                                                 const float* __restrict__ cmat,
                                                 float* __restrict__ vbuf,
                                                 float* __restrict__ out,
                                                 int write_out)
{
    __shared__ __align__(16) float xL[NI_ * DI_];  // 36 KB, xL[i*8+d] = x[b,d,i]
    __shared__ float sred[SEGS_ * PAIRS_];
    __shared__ float sfin[PAIRS_];
    int b = blockIdx.x;
    {
        const float4* xs = (const float4*)(x + (size_t)b * NI_ * DI_);
        for (int t = threadIdx.x; t < NI_ * DI_ / 4; t += 640) {
            float4 v4 = xs[t];                // 4 consecutive i in one d-row
            int f = 4 * t;
            int d = f / NI_;
            int i = f - d * NI_;              // multiple of 4; row-safe (NI_ % 4 == 0)
            xL[i * DI_ + d]       = v4.x;
            xL[(i + 1) * DI_ + d] = v4.y;
            xL[(i + 2) * DI_ + d] = v4.z;
            xL[(i + 3) * DI_ + d] = v4.w;
        }
    }
    __syncthreads();

    int pair = threadIdx.x % PAIRS_;
    int seg  = threadIdx.x / PAIRS_;
    int j    = pair >> 4;
    const float4* Wq = (const float4*)W;   // W[i,j,o,0:4] / [4:8] per float4
    float acc = 0.f;
    int i0 = seg * IPS_;
    for (int i = i0; i < i0 + IPS_; ++i) {
        float4 w0 = Wq[(i * PAIRS_ + pair) * 2];
        float4 w1 = Wq[(i * PAIRS_ + pair) * 2 + 1];
        const float* xp = &xL[i * DI_];              // broadcast (same addr all lanes)
        float u = w0.x * xp[0] + w0.y * xp[1] + w0.z * xp[2] + w0.w * xp[3]
                + w1.x * xp[4] + w1.y * xp[5] + w1.z * xp[6] + w1.w * xp[7];
        acc = fmaf(cmat[i * NO_ + j], u, acc);
    }
    sred[threadIdx.x] = acc;
    __syncthreads();                                 // uniform
    float s = 0.f;
    if (threadIdx.x < PAIRS_) {
        s = sred[threadIdx.x] + sred[PAIRS_ + threadIdx.x]
          + sred[2 * PAIRS_ + threadIdx.x] + sred[3 * PAIRS_ + threadIdx.x];
        sfin[threadIdx.x] = s;
    }
    __syncthreads();                                 // uniform
    if (threadIdx.x < PAIRS_) {
        int jj = threadIdx.x >> 4;
        float sq = 0.f;
#pragma unroll
        for (int o = 0; o < DO_; ++o) { float t = sfin[(jj << 4) + o]; sq = fmaf(t, t, sq); }
        float vv = s * (sq / (1.f + sq)) * rsqrtf(sq + 1e-9f);
        vbuf[b * PAIRS_ + threadIdx.x] = vv;
        if (write_out) out[b * PAIRS_ + threadIdx.x] = vv;
    }
}

// One block per input capsule i; thread = batch item b. Recomputes u_hat[b,i,:,:]
// from LDS-staged W[i] and x[b,:,i], dots with v, reduces mean over batch into blog.
__global__ __launch_bounds__(256) void agree_kernel(const float* __restrict__ x,
                                                    const float* __restrict__ W,
                                                    const float* __restrict__ vbuf,
                                                    float* __restrict__ blog)
{
    int i = blockIdx.x;
    __shared__ float Wf[NO_ * DO_ * DI_];  // 1280 floats = 5 KB
    {
        const float* Wp = W + (size_t)i * NO_ * DO_ * DI_;
        for (int t = threadIdx.x; t < NO_ * DO_ * DI_; t += 256)
            Wf[t] = Wp[t];
    }
    __syncthreads();
    int b = threadIdx.x;
    float xr[DI_];
#pragma unroll
    for (int d = 0; d < DI_; ++d)
        xr[d] = x[((size_t)b * DI_ + d) * NI_ + i];
    float accj[NO_];
#pragma unroll
    for (int j = 0; j < NO_; ++j) {
        const float* vp = &vbuf[b * PAIRS_ + j * DO_];
        float aj = 0.f;
#pragma unroll
        for (int o = 0; o < DO_; ++o) {
            const float* wf = &Wf[(j * DO_ + o) * DI_];  // broadcast reads
            float u = wf[0] * xr[0] + wf[1] * xr[1] + wf[2] * xr[2] + wf[3] * xr[3]
                    + wf[4] * xr[4] + wf[5] * xr[5] + wf[6] * xr[6] + wf[7] * xr[7];
            aj = fmaf(u, vp[o], aj);
        }
        accj[j] = aj;
    }
    __shared__ float red[4][NO_];
    int lane = threadIdx.x & 63;
    int wv   = threadIdx.x >> 6;
#pragma unroll
    for (int j = 0; j < NO_; ++j) {
        float val = accj[j];
        for (int off = 32; off > 0; off >>= 1) val += __shfl_down(val, off);
        if (lane == 0) red[wv][j] = val;
    }
    __syncthreads();
    if (threadIdx.x < NO_) {
        float sum = red[0][threadIdx.x] + red[1][threadIdx.x]
                  + red[2][threadIdx.x] + red[3][threadIdx.x];
        blog[i * NO_ + threadIdx.x] += sum * (1.f / B_);
    }
}

extern "C" void kernel_launch(void* const* d_in, const int* in_sizes, int n_in,
                              void* d_out, int out_size, void* d_ws, size_t ws_size,
                              hipStream_t stream)
{
    const float* x = (const float*)d_in[0];   // [256,8,1152] fp32
    const float* W = (const float*)d_in[1];   // [1152,10,16,8] fp32
    float* out = (float*)d_out;               // [256,10,16] fp32

    // ws layout (fp32): blog [NI,NO] | cmat [NI,NO] | vbuf [B,NO,DO]  (~256 KB)
    float* blog = (float*)d_ws;
    float* cmat = blog + NI_ * NO_;
    float* vbuf = cmat + NI_ * NO_;

    for (int it = 0; it < 3; ++it) {
        c_kernel<<<(NI_ + 255) / 256, 256, 0, stream>>>(blog, cmat, it == 0 ? 1 : 0);
        sv_kernel<<<B_, 640, 0, stream>>>(x, W, cmat, vbuf, out, it == 2 ? 1 : 0);
        if (it < 2) agree_kernel<<<NI_, 256, 0, stream>>>(x, W, vbuf, blog);
    }
}

// Round 5
// 298.942 us; speedup vs baseline: 4.7386x; 4.7386x over previous
//
#include <hip/hip_runtime.h>

#define B_     256
#define NI_    1152
#define NO_    10
#define DO_    16
#define DI_    8
#define PAIRS_ 160          // NO_*DO_
#define SEGS_  128          // i-segments for sv partial reduction (fast path)
#define ISEG_  (NI_/SEGS_)  // 9
#define BG_    4            // batch groups of 64
#define PPT_   40           // pairs per thread-group (160/4)

// ===================== shared =====================

// iter 0: cmat = 0.1 (softmax of zeros), blog = 0.   iter>0: cmat = softmax(blog).
__global__ __launch_bounds__(256) void c_kernel(float* __restrict__ blog,
                                                float* __restrict__ cmat,
                                                int init)
{
    int i = blockIdx.x * 256 + threadIdx.x;
    if (i >= NI_) return;
    if (init) {
#pragma unroll
        for (int j = 0; j < NO_; ++j) { cmat[i * NO_ + j] = 0.1f; blog[i * NO_ + j] = 0.f; }
        return;
    }
    float r[NO_];
    float m = -1e30f;
#pragma unroll
    for (int j = 0; j < NO_; ++j) { r[j] = blog[i * NO_ + j]; m = fmaxf(m, r[j]); }
    float s = 0.f;
#pragma unroll
    for (int j = 0; j < NO_; ++j) { r[j] = __expf(r[j] - m); s += r[j]; }
    float inv = 1.f / s;
#pragma unroll
    for (int j = 0; j < NO_; ++j) cmat[i * NO_ + j] = r[j] * inv;
}

// ===================== fast path =====================

// x[b,d,i] -> xT[(i*8+d)*256 + b]. Reads scattered (L2/L3 absorbs), writes coalesced.
__global__ __launch_bounds__(256) void prep_kernel(const float* __restrict__ x,
                                                   float* __restrict__ xT)
{
    int g = blockIdx.x * 256 + threadIdx.x;      // over 9216*256
    int b = g & 255;
    int r = g >> 8;
    int d = r & 7;
    int i = r >> 3;
    xT[g] = x[(size_t)b * (NI_ * DI_) + d * NI_ + i];
}

// Block = (bg, seg): 64 batch items x 9 input capsules, all 160 pairs.
// Lanes = b (coalesced xT vector loads); W/c addresses wave-uniform -> SMEM.
// No LDS, no barriers. acc[40] per thread.
__global__ __launch_bounds__(256) void sv_kernel(const float* __restrict__ xT,
                                                 const float* __restrict__ W,
                                                 const float* __restrict__ cmat,
                                                 float* __restrict__ partial)
{
    int bg  = blockIdx.x;                 // 0..3
    int seg = blockIdx.y;                 // 0..127
    int b_l = threadIdx.x & 63;
    int pg  = __builtin_amdgcn_readfirstlane(threadIdx.x >> 6);   // wave-uniform pair group
    int b   = bg * 64 + b_l;
    int p0  = pg * PPT_;

    float acc[PPT_];
#pragma unroll
    for (int p = 0; p < PPT_; ++p) acc[p] = 0.f;

    for (int ii = 0; ii < ISEG_; ++ii) {
        int i = seg * ISEG_ + ii;
        float xv[DI_];
#pragma unroll
        for (int d = 0; d < DI_; ++d)
            xv[d] = xT[(i * DI_ + d) * B_ + b];            // coalesced vector load
        const float* __restrict__ crow = cmat + i * NO_;    // uniform
        const float* __restrict__ wbase = W + (size_t)(i * PAIRS_ + p0) * DI_;  // uniform
#pragma unroll
        for (int p = 0; p < PPT_; ++p) {
            const float* wr = wbase + p * DI_;              // uniform -> s_load
            float u = wr[0] * xv[0] + wr[1] * xv[1] + wr[2] * xv[2] + wr[3] * xv[3]
                    + wr[4] * xv[4] + wr[5] * xv[5] + wr[6] * xv[6] + wr[7] * xv[7];
            acc[p] = fmaf(crow[(p0 + p) >> 4], u, acc[p]);
        }
    }
#pragma unroll
    for (int p = 0; p < PPT_; ++p)
        partial[(size_t)(seg * PAIRS_ + p0 + p) * B_ + b] = acc[p];   // coalesced
}

// Reduce partials over segments, squash over o, write v (and final output).
// Grid (10 j, 16 b-chunks); threads 256 = 16 o x 16 b.
__global__ __launch_bounds__(256) void red_kernel(const float* __restrict__ partial,
                                                  float* __restrict__ vbuf,
                                                  float* __restrict__ out,
                                                  int write_out)
{
    int j  = blockIdx.x;
    int bc = blockIdx.y;
    int o   = threadIdx.x >> 4;
    int b_l = threadIdx.x & 15;
    int b   = bc * 16 + b_l;
    int pair = j * DO_ + o;

    float s = 0.f;
    for (int seg = 0; seg < SEGS_; ++seg)
        s += partial[(size_t)(seg * PAIRS_ + pair) * B_ + b];

    __shared__ float sqs[DO_][17];
    sqs[o][b_l] = s * s;
    __syncthreads();
    float sq = 0.f;
#pragma unroll
    for (int oo = 0; oo < DO_; ++oo) sq += sqs[oo][b_l];
    float vv = s * (sq / (1.f + sq)) * rsqrtf(sq + 1e-9f);
    vbuf[pair * B_ + b] = vv;
    if (write_out) out[(size_t)b * PAIRS_ + pair] = vv;
}

// Block per i; lanes = b. xT/vbuf reads coalesced, W reads wave-uniform (SMEM).
// Serial j-loop: ~30 VGPR, no spills.
__global__ __launch_bounds__(256) void agree_kernel(const float* __restrict__ xT,
                                                    const float* __restrict__ W,
                                                    const float* __restrict__ vbuf,
                                                    float* __restrict__ blog)
{
    int i = blockIdx.x;
    int b = threadIdx.x;
    float xv[DI_];
#pragma unroll
    for (int d = 0; d < DI_; ++d)
        xv[d] = xT[(i * DI_ + d) * B_ + b];                 // coalesced

    __shared__ float red[4][NO_];
    int lane = threadIdx.x & 63;
    int wv   = threadIdx.x >> 6;

    for (int j = 0; j < NO_; ++j) {
        float aj = 0.f;
#pragma unroll
        for (int o = 0; o < DO_; ++o) {
            const float* wr = W + (size_t)((i * NO_ + j) * DO_ + o) * DI_;  // uniform
            float u = wr[0] * xv[0] + wr[1] * xv[1] + wr[2] * xv[2] + wr[3] * xv[3]
                    + wr[4] * xv[4] + wr[5] * xv[5] + wr[6] * xv[6] + wr[7] * xv[7];
            aj = fmaf(u, vbuf[(j * DO_ + o) * B_ + b], aj); // coalesced
        }
        float val = aj;
        for (int off = 32; off > 0; off >>= 1) val += __shfl_down(val, off);
        if (lane == 0) red[wv][j] = val;
    }
    __syncthreads();
    if (threadIdx.x < NO_) {
        float sum = red[0][threadIdx.x] + red[1][threadIdx.x]
                  + red[2][threadIdx.x] + red[3][threadIdx.x];
        blog[i * NO_ + threadIdx.x] += sum * (1.f / B_);
    }
}

// ===================== fallback path (proven R4 kernels, ws < 31 MB) =====================

__global__ __launch_bounds__(640) void sv_old(const float* __restrict__ x,
                                              const float* __restrict__ W,
                                              const float* __restrict__ cmat,
                                              float* __restrict__ vbuf,
                                              float* __restrict__ out,
                                              int write_out)
{
    __shared__ __align__(16) float xL[NI_ * DI_];
    __shared__ float sred[4 * PAIRS_];
    __shared__ float sfin[PAIRS_];
    int b = blockIdx.x;
    {
        const float4* xs = (const float4*)(x + (size_t)b * NI_ * DI_);
        for (int t = threadIdx.x; t < NI_ * DI_ / 4; t += 640) {
            float4 v4 = xs[t];
            int f = 4 * t;
            int d = f / NI_;
            int i = f - d * NI_;
            xL[i * DI_ + d] = v4.x; xL[(i+1) * DI_ + d] = v4.y;
            xL[(i+2) * DI_ + d] = v4.z; xL[(i+3) * DI_ + d] = v4.w;
        }
    }
    __syncthreads();
    int pair = threadIdx.x % PAIRS_;
    int seg  = threadIdx.x / PAIRS_;
    int j    = pair >> 4;
    const float4* Wq = (const float4*)W;
    float acc = 0.f;
    int i0 = seg * (NI_ / 4);
    for (int i = i0; i < i0 + NI_ / 4; ++i) {
        float4 w0 = Wq[(i * PAIRS_ + pair) * 2];
        float4 w1 = Wq[(i * PAIRS_ + pair) * 2 + 1];
        const float* xp = &xL[i * DI_];
        float u = w0.x * xp[0] + w0.y * xp[1] + w0.z * xp[2] + w0.w * xp[3]
                + w1.x * xp[4] + w1.y * xp[5] + w1.z * xp[6] + w1.w * xp[7];
        acc = fmaf(cmat[i * NO_ + j], u, acc);
    }
    sred[threadIdx.x] = acc;
    __syncthreads();
    float s = 0.f;
    if (threadIdx.x < PAIRS_) {
        s = sred[threadIdx.x] + sred[PAIRS_ + threadIdx.x]
          + sred[2 * PAIRS_ + threadIdx.x] + sred[3 * PAIRS_ + threadIdx.x];
        sfin[threadIdx.x] = s;
    }
    __syncthreads();
    if (threadIdx.x < PAIRS_) {
        int jj = threadIdx.x >> 4;
        float sq = 0.f;
#pragma unroll
        for (int o = 0; o < DO_; ++o) { float t = sfin[(jj << 4) + o]; sq = fmaf(t, t, sq); }
        float vv = s * (sq / (1.f + sq)) * rsqrtf(sq + 1e-9f);
        vbuf[b * PAIRS_ + threadIdx.x] = vv;
        if (write_out) out[b * PAIRS_ + threadIdx.x] = vv;
    }
}

__global__ __launch_bounds__(256) void agree_old(const float* __restrict__ x,
                                                 const float* __restrict__ W,
                                                 const float* __restrict__ vbuf,
                                                 float* __restrict__ blog)
{
    int i = blockIdx.x;
    __shared__ float Wf[NO_ * DO_ * DI_];
    {
        const float* Wp = W + (size_t)i * NO_ * DO_ * DI_;
        for (int t = threadIdx.x; t < NO_ * DO_ * DI_; t += 256) Wf[t] = Wp[t];
    }
    __syncthreads();
    int b = threadIdx.x;
    float xr[DI_];
#pragma unroll
    for (int d = 0; d < DI_; ++d) xr[d] = x[((size_t)b * DI_ + d) * NI_ + i];
    __shared__ float red[4][NO_];
    int lane = threadIdx.x & 63;
    int wv   = threadIdx.x >> 6;
    for (int j = 0; j < NO_; ++j) {
        const float* vp = &vbuf[b * PAIRS_ + j * DO_];
        float aj = 0.f;
#pragma unroll
        for (int o = 0; o < DO_; ++o) {
            const float* wf = &Wf[(j * DO_ + o) * DI_];
            float u = wf[0] * xr[0] + wf[1] * xr[1] + wf[2] * xr[2] + wf[3] * xr[3]
                    + wf[4] * xr[4] + wf[5] * xr[5] + wf[6] * xr[6] + wf[7] * xr[7];
            aj = fmaf(u, vp[o], aj);
        }
        float val = aj;
        for (int off = 32; off > 0; off >>= 1) val += __shfl_down(val, off);
        if (lane == 0) red[wv][j] = val;
    }
    __syncthreads();
    if (threadIdx.x < NO_) {
        float sum = red[0][threadIdx.x] + red[1][threadIdx.x]
                  + red[2][threadIdx.x] + red[3][threadIdx.x];
        blog[i * NO_ + threadIdx.x] += sum * (1.f / B_);
    }
}

// ===================== launch =====================

extern "C" void kernel_launch(void* const* d_in, const int* in_sizes, int n_in,
                              void* d_out, int out_size, void* d_ws, size_t ws_size,
                              hipStream_t stream)
{
    const float* x = (const float*)d_in[0];   // [256,8,1152]
    const float* W = (const float*)d_in[1];   // [1152,10,16,8]
    float* out = (float*)d_out;               // [256,10,16]

    // fast-path ws: xT | blog | cmat | vbuf[pair][b] | partial[seg][pair][b]
    const size_t XT_N = (size_t)NI_ * DI_ * B_;          // 2,359,296
    const size_t LOG_N = NI_ * NO_;                      // 11,520
    const size_t V_N = PAIRS_ * B_;                      // 40,960
    const size_t P_N = (size_t)SEGS_ * PAIRS_ * B_;      // 5,242,880
    const size_t NEED = (XT_N + 2 * LOG_N + V_N + P_N) * sizeof(float);  // ~30.7 MB

    if (ws_size >= NEED) {
        float* xT      = (float*)d_ws;
        float* blog    = xT + XT_N;
        float* cmat    = blog + LOG_N;
        float* vbuf    = cmat + LOG_N;
        float* partial = vbuf + V_N;

        prep_kernel<<<(NI_ * DI_ * B_) / 256, 256, 0, stream>>>(x, xT);
        for (int it = 0; it < 3; ++it) {
            c_kernel<<<(NI_ + 255) / 256, 256, 0, stream>>>(blog, cmat, it == 0 ? 1 : 0);
            sv_kernel<<<dim3(BG_, SEGS_), 256, 0, stream>>>(xT, W, cmat, partial);
            red_kernel<<<dim3(NO_, B_ / 16), 256, 0, stream>>>(partial, vbuf, out,
                                                               it == 2 ? 1 : 0);
            if (it < 2) agree_kernel<<<NI_, 256, 0, stream>>>(xT, W, vbuf, blog);
        }
    } else {
        float* blog = (float*)d_ws;
        float* cmat = blog + LOG_N;
        float* vbuf = cmat + LOG_N;
        for (int it = 0; it < 3; ++it) {
            c_kernel<<<(NI_ + 255) / 256, 256, 0, stream>>>(blog, cmat, it == 0 ? 1 : 0);
            sv_old<<<B_, 640, 0, stream>>>(x, W, cmat, vbuf, out, it == 2 ? 1 : 0);
            if (it < 2) agree_old<<<NI_, 256, 0, stream>>>(x, W, vbuf, blog);
        }
    }
}

// Round 6
// 243.085 us; speedup vs baseline: 5.8274x; 1.2298x over previous
//
#include <hip/hip_runtime.h>

#define B_     256
#define NI_    1152
#define NO_    10
#define DO_    16
#define DI_    8
#define PAIRS_ 160          // NO_*DO_
#define SEGS_  128          // i-segments for sv partial reduction
#define ISEG_  (NI_/SEGS_)  // 9
#define PP_    10           // pairs per thread (sv)
#define TB_    4            // batch elements per thread (b = lane + 64*r)

// ===================== shared =====================

// iter 0: cmat = 0.1 (softmax of zeros), blog = 0.   iter>0: cmat = softmax(blog).
__global__ __launch_bounds__(256) void c_kernel(float* __restrict__ blog,
                                                float* __restrict__ cmat,
                                                int init)
{
    int i = blockIdx.x * 256 + threadIdx.x;
    if (i >= NI_) return;
    if (init) {
#pragma unroll
        for (int j = 0; j < NO_; ++j) { cmat[i * NO_ + j] = 0.1f; blog[i * NO_ + j] = 0.f; }
        return;
    }
    float r[NO_];
    float m = -1e30f;
#pragma unroll
    for (int j = 0; j < NO_; ++j) { r[j] = blog[i * NO_ + j]; m = fmaxf(m, r[j]); }
    float s = 0.f;
#pragma unroll
    for (int j = 0; j < NO_; ++j) { r[j] = __expf(r[j] - m); s += r[j]; }
    float inv = 1.f / s;
#pragma unroll
    for (int j = 0; j < NO_; ++j) cmat[i * NO_ + j] = r[j] * inv;
}

// x[b,d,i] -> xT[(i*8+d)*256 + b]. Reads scattered (L2/L3 absorbs), writes coalesced.
__global__ __launch_bounds__(256) void prep_kernel(const float* __restrict__ x,
                                                   float* __restrict__ xT)
{
    int g = blockIdx.x * 256 + threadIdx.x;      // over 9216*256
    int b = g & 255;
    int r = g >> 8;
    int d = r & 7;
    int i = r >> 3;
    xT[g] = x[(size_t)b * (NI_ * DI_) + d * NI_ + i];
}

// ===================== fast path =====================

// Block = (ps, seg). 4 waves; wave pg covers pairs [ps*40+pg*10, +10).
// Lanes = b (TB_=4 regs -> all 256 b per wave). W/c wave-uniform -> s_load,
// each scalar W value feeds TB_ fmas (4x less SMEM pressure per VALU op than R5).
__global__ __launch_bounds__(256) void sv_kernel(const float* __restrict__ xT,
                                                 const float* __restrict__ W,
                                                 const float* __restrict__ cmat,
                                                 float* __restrict__ partial)
{
    int ps   = blockIdx.x;                // 0..3
    int seg  = blockIdx.y;                // 0..SEGS_-1
    int lane = threadIdx.x & 63;
    int pg   = __builtin_amdgcn_readfirstlane(threadIdx.x >> 6);  // wave-uniform
    int p0   = ps * (4 * PP_) + pg * PP_;

    float acc[PP_][TB_];
#pragma unroll
    for (int p = 0; p < PP_; ++p)
#pragma unroll
        for (int r = 0; r < TB_; ++r) acc[p][r] = 0.f;

    for (int ii = 0; ii < ISEG_; ++ii) {
        int i = seg * ISEG_ + ii;
        float xv[DI_][TB_];
#pragma unroll
        for (int d = 0; d < DI_; ++d)
#pragma unroll
            for (int r = 0; r < TB_; ++r)
                xv[d][r] = xT[(i * DI_ + d) * B_ + r * 64 + lane];   // coalesced
        const float* __restrict__ crow = cmat + i * NO_;              // uniform
        const float* __restrict__ wb = W + (size_t)(i * PAIRS_ + p0) * DI_;  // uniform
#pragma unroll
        for (int p = 0; p < PP_; ++p) {
            const float* wr = wb + p * DI_;                           // s_load x8
            float cv = crow[(p0 + p) >> 4];
#pragma unroll
            for (int r = 0; r < TB_; ++r) {
                float u = wr[0] * xv[0][r] + wr[1] * xv[1][r]
                        + wr[2] * xv[2][r] + wr[3] * xv[3][r]
                        + wr[4] * xv[4][r] + wr[5] * xv[5][r]
                        + wr[6] * xv[6][r] + wr[7] * xv[7][r];
                acc[p][r] = fmaf(cv, u, acc[p][r]);
            }
        }
    }
#pragma unroll
    for (int p = 0; p < PP_; ++p)
#pragma unroll
        for (int r = 0; r < TB_; ++r)
            partial[(size_t)(seg * PAIRS_ + p0 + p) * B_ + r * 64 + lane] = acc[p][r];
}

// Reduce partials over segments, squash over o, write v[pair][b] (and final out).
__global__ __launch_bounds__(256) void red_kernel(const float* __restrict__ partial,
                                                  float* __restrict__ vbuf,
                                                  float* __restrict__ out,
                                                  int write_out)
{
    int j  = blockIdx.x;
    int bc = blockIdx.y;
    int o   = threadIdx.x >> 4;
    int b_l = threadIdx.x & 15;
    int b   = bc * 16 + b_l;
    int pair = j * DO_ + o;

    float s = 0.f;
    for (int seg = 0; seg < SEGS_; ++seg)
        s += partial[(size_t)(seg * PAIRS_ + pair) * B_ + b];

    __shared__ float sqs[DO_][17];
    sqs[o][b_l] = s * s;
    __syncthreads();
    float sq = 0.f;
#pragma unroll
    for (int oo = 0; oo < DO_; ++oo) sq += sqs[oo][b_l];
    float vv = s * (sq / (1.f + sq)) * rsqrtf(sq + 1e-9f);
    vbuf[pair * B_ + b] = vv;
    if (write_out) out[(size_t)b * PAIRS_ + pair] = vv;
}

// Block = 4 i's (one wave per i). Lanes = b, TB_=4 regs. W wave-uniform (s_load),
// xT/vbuf coalesced. Wave-reduce per (i,j), lane0 updates blog (each wave owns its i).
__global__ __launch_bounds__(256) void agree_kernel(const float* __restrict__ xT,
                                                    const float* __restrict__ W,
                                                    const float* __restrict__ vbuf,
                                                    float* __restrict__ blog)
{
    int wv   = __builtin_amdgcn_readfirstlane(threadIdx.x >> 6);  // wave-uniform
    int i    = blockIdx.x * 4 + wv;
    int lane = threadIdx.x & 63;

    float xv[DI_][TB_];
#pragma unroll
    for (int d = 0; d < DI_; ++d)
#pragma unroll
        for (int r = 0; r < TB_; ++r)
            xv[d][r] = xT[(i * DI_ + d) * B_ + r * 64 + lane];     // coalesced

    for (int j = 0; j < NO_; ++j) {
        float aj = 0.f;
        const float* __restrict__ wj = W + (size_t)(i * NO_ + j) * DO_ * DI_;  // uniform
#pragma unroll
        for (int o = 0; o < DO_; ++o) {
            const float* wr = wj + o * DI_;                         // s_load x8
            const float* vp = vbuf + (j * DO_ + o) * B_;
#pragma unroll
            for (int r = 0; r < TB_; ++r) {
                float u = wr[0] * xv[0][r] + wr[1] * xv[1][r]
                        + wr[2] * xv[2][r] + wr[3] * xv[3][r]
                        + wr[4] * xv[4][r] + wr[5] * xv[5][r]
                        + wr[6] * xv[6][r] + wr[7] * xv[7][r];
                aj = fmaf(u, vp[r * 64 + lane], aj);                // coalesced
            }
        }
        for (int off = 32; off > 0; off >>= 1) aj += __shfl_down(aj, off);
        if (lane == 0) blog[i * NO_ + j] += aj * (1.f / B_);
    }
}

// ===================== fallback path (proven R4 kernels, small ws) =====================

__global__ __launch_bounds__(640) void sv_old(const float* __restrict__ x,
                                              const float* __restrict__ W,
                                              const float* __restrict__ cmat,
                                              float* __restrict__ vbuf,
                                              float* __restrict__ out,
                                              int write_out)
{
    __shared__ __align__(16) float xL[NI_ * DI_];
    __shared__ float sred[4 * PAIRS_];
    __shared__ float sfin[PAIRS_];
    int b = blockIdx.x;
    {
        const float4* xs = (const float4*)(x + (size_t)b * NI_ * DI_);
        for (int t = threadIdx.x; t < NI_ * DI_ / 4; t += 640) {
            float4 v4 = xs[t];
            int f = 4 * t;
            int d = f / NI_;
            int i = f - d * NI_;
            xL[i * DI_ + d] = v4.x; xL[(i+1) * DI_ + d] = v4.y;
            xL[(i+2) * DI_ + d] = v4.z; xL[(i+3) * DI_ + d] = v4.w;
        }
    }
    __syncthreads();
    int pair = threadIdx.x % PAIRS_;
    int seg  = threadIdx.x / PAIRS_;
    int j    = pair >> 4;
    const float4* Wq = (const float4*)W;
    float acc = 0.f;
    int i0 = seg * (NI_ / 4);
    for (int i = i0; i < i0 + NI_ / 4; ++i) {
        float4 w0 = Wq[(i * PAIRS_ + pair) * 2];
        float4 w1 = Wq[(i * PAIRS_ + pair) * 2 + 1];
        const float* xp = &xL[i * DI_];
        float u = w0.x * xp[0] + w0.y * xp[1] + w0.z * xp[2] + w0.w * xp[3]
                + w1.x * xp[4] + w1.y * xp[5] + w1.z * xp[6] + w1.w * xp[7];
        acc = fmaf(cmat[i * NO_ + j], u, acc);
    }
    sred[threadIdx.x] = acc;
    __syncthreads();
    float s = 0.f;
    if (threadIdx.x < PAIRS_) {
        s = sred[threadIdx.x] + sred[PAIRS_ + threadIdx.x]
          + sred[2 * PAIRS_ + threadIdx.x] + sred[3 * PAIRS_ + threadIdx.x];
        sfin[threadIdx.x] = s;
    }
    __syncthreads();
    if (threadIdx.x < PAIRS_) {
        int jj = threadIdx.x >> 4;
        float sq = 0.f;
#pragma unroll
        for (int o = 0; o < DO_; ++o) { float t = sfin[(jj << 4) + o]; sq = fmaf(t, t, sq); }
        float vv = s * (sq / (1.f + sq)) * rsqrtf(sq + 1e-9f);
        vbuf[b * PAIRS_ + threadIdx.x] = vv;
        if (write_out) out[b * PAIRS_ + threadIdx.x] = vv;
    }
}

__global__ __launch_bounds__(256) void agree_old(const float* __restrict__ x,
                                                 const float* __restrict__ W,
                                                 const float* __restrict__ vbuf,
                                                 float* __restrict__ blog)
{
    int i = blockIdx.x;
    int b = threadIdx.x;
    float xr[DI_];
#pragma unroll
    for (int d = 0; d < DI_; ++d) xr[d] = x[((size_t)b * DI_ + d) * NI_ + i];
    __shared__ float red[4][NO_];
    int lane = threadIdx.x & 63;
    int wv   = threadIdx.x >> 6;
    for (int j = 0; j < NO_; ++j) {
        const float* vp = &vbuf[b * PAIRS_ + j * DO_];
        float aj = 0.f;
#pragma unroll
        for (int o = 0; o < DO_; ++o) {
            const float* wr = W + (size_t)((i * NO_ + j) * DO_ + o) * DI_;
            float u = wr[0] * xr[0] + wr[1] * xr[1] + wr[2] * xr[2] + wr[3] * xr[3]
                    + wr[4] * xr[4] + wr[5] * xr[5] + wr[6] * xr[6] + wr[7] * xr[7];
            aj = fmaf(u, vp[o], aj);
        }
        float val = aj;
        for (int off = 32; off > 0; off >>= 1) val += __shfl_down(val, off);
        if (lane == 0) red[wv][j] = val;
    }
    __syncthreads();
    if (threadIdx.x < NO_) {
        float sum = red[0][threadIdx.x] + red[1][threadIdx.x]
                  + red[2][threadIdx.x] + red[3][threadIdx.x];
        blog[i * NO_ + threadIdx.x] += sum * (1.f / B_);
    }
}

// ===================== launch =====================

extern "C" void kernel_launch(void* const* d_in, const int* in_sizes, int n_in,
                              void* d_out, int out_size, void* d_ws, size_t ws_size,
                              hipStream_t stream)
{
    const float* x = (const float*)d_in[0];   // [256,8,1152]
    const float* W = (const float*)d_in[1];   // [1152,10,16,8]
    float* out = (float*)d_out;               // [256,10,16]

    const size_t XT_N = (size_t)NI_ * DI_ * B_;          // 2,359,296
    const size_t LOG_N = NI_ * NO_;                      // 11,520
    const size_t V_N = PAIRS_ * B_;                      // 40,960
    const size_t P_N = (size_t)SEGS_ * PAIRS_ * B_;      // 5,242,880
    const size_t NEED = (XT_N + 2 * LOG_N + V_N + P_N) * sizeof(float);  // ~29.3 MiB

    if (ws_size >= NEED) {
        float* xT      = (float*)d_ws;
        float* blog    = xT + XT_N;
        float* cmat    = blog + LOG_N;
        float* vbuf    = cmat + LOG_N;
        float* partial = vbuf + V_N;

        prep_kernel<<<(NI_ * DI_ * B_) / 256, 256, 0, stream>>>(x, xT);
        for (int it = 0; it < 3; ++it) {
            c_kernel<<<(NI_ + 255) / 256, 256, 0, stream>>>(blog, cmat, it == 0 ? 1 : 0);
            sv_kernel<<<dim3(4, SEGS_), 256, 0, stream>>>(xT, W, cmat, partial);
            red_kernel<<<dim3(NO_, B_ / 16), 256, 0, stream>>>(partial, vbuf, out,
                                                               it == 2 ? 1 : 0);
            if (it < 2) agree_kernel<<<NI_ / 4, 256, 0, stream>>>(xT, W, vbuf, blog);
        }
    } else {
        float* blog = (float*)d_ws;
        float* cmat = blog + LOG_N;
        float* vbuf = cmat + LOG_N;
        for (int it = 0; it < 3; ++it) {
            c_kernel<<<(NI_ + 255) / 256, 256, 0, stream>>>(blog, cmat, it == 0 ? 1 : 0);
            sv_old<<<B_, 640, 0, stream>>>(x, W, cmat, vbuf, out, it == 2 ? 1 : 0);
            if (it < 2) agree_old<<<NI_, 256, 0, stream>>>(x, W, vbuf, blog);
        }
    }
}

// Round 7
// 188.695 us; speedup vs baseline: 7.5072x; 1.2882x over previous
//
#include <hip/hip_runtime.h>

#define B_     256
#define NI_    1152
#define NO_    10
#define DO_    16
#define DI_    8
#define PAIRS_ 160          // NO_*DO_
#define SEGS_  128          // i-segments for sv partial reduction
#define ISEG_  (NI_/SEGS_)  // 9
#define PP_    5            // pairs per wave (sv)
#define SC_    4            // seg chunks in red1

// ===================== fast path =====================

// x[b,d,i] -> xT[(i*8+d)*256 + b]; also init blog=0, cmat=0.1 (softmax of zeros).
__global__ __launch_bounds__(256) void prep_kernel(const float* __restrict__ x,
                                                   float* __restrict__ xT,
                                                   float* __restrict__ blog,
                                                   float* __restrict__ cmat)
{
    int g = blockIdx.x * 256 + threadIdx.x;      // over 9216*256
    int b = g & 255;
    int r = g >> 8;
    int d = r & 7;
    int i = r >> 3;
    xT[g] = x[(size_t)b * (NI_ * DI_) + d * NI_ + i];
    if (g < NI_ * NO_) { blog[g] = 0.f; cmat[g] = 0.1f; }
}

// Block = (ps 0..7, seg 0..127); 4 waves. Wave pg covers pairs [ps*20+pg*5, +5).
// Lanes hold b = 4*lane..+3 (float4). Each x-row staged once in LDS (shared by
// 4 waves), prefetch-pipelined with ONE barrier per i. W/c wave-uniform -> s_load.
__global__ __launch_bounds__(256) void sv_kernel(const float* __restrict__ xT,
                                                 const float* __restrict__ W,
                                                 const float* __restrict__ cmat,
                                                 float* __restrict__ partial)
{
    __shared__ __align__(16) float xs[2][DI_ * B_];   // 2 x 8 KB
    int ps   = blockIdx.x;
    int seg  = blockIdx.y;
    int tid  = threadIdx.x;
    int lane = tid & 63;
    int pg   = __builtin_amdgcn_readfirstlane(tid >> 6);
    int p0   = ps * (4 * PP_) + pg * PP_;
    int b0   = lane * 4;
    int i0   = seg * ISEG_;

    float acc[PP_][4];
#pragma unroll
    for (int p = 0; p < PP_; ++p)
#pragma unroll
        for (int r = 0; r < 4; ++r) acc[p][r] = 0.f;

    float4 nx0, nx1;
    {
        const float4* src = (const float4*)(xT + (size_t)i0 * (DI_ * B_));
        nx0 = src[tid * 2];
        nx1 = src[tid * 2 + 1];
    }
    int buf = 0;
    for (int ii = 0; ii < ISEG_; ++ii) {
        int i = i0 + ii;
        ((float4*)xs[buf])[tid * 2]     = nx0;
        ((float4*)xs[buf])[tid * 2 + 1] = nx1;
        __syncthreads();                              // single barrier per i (safe:
        if (ii + 1 < ISEG_) {                         // next store goes to buf^1)
            const float4* src = (const float4*)(xT + (size_t)(i + 1) * (DI_ * B_));
            nx0 = src[tid * 2];
            nx1 = src[tid * 2 + 1];
        }
        float xv[DI_][4];
#pragma unroll
        for (int d = 0; d < DI_; ++d) {
            float4 t4 = *(const float4*)&xs[buf][d * B_ + b0];   // ds_read_b128
            xv[d][0] = t4.x; xv[d][1] = t4.y; xv[d][2] = t4.z; xv[d][3] = t4.w;
        }
        const float* __restrict__ crow = cmat + i * NO_;                       // uniform
        const float* __restrict__ wb = W + (size_t)(i * PAIRS_ + p0) * DI_;    // uniform
#pragma unroll
        for (int p = 0; p < PP_; ++p) {
            const float* wr = wb + p * DI_;                                    // s_load x8
            float cv = crow[(p0 + p) >> 4];
#pragma unroll
            for (int r = 0; r < 4; ++r) {
                float u = wr[0] * xv[0][r] + wr[1] * xv[1][r]
                        + wr[2] * xv[2][r] + wr[3] * xv[3][r]
                        + wr[4] * xv[4][r] + wr[5] * xv[5][r]
                        + wr[6] * xv[6][r] + wr[7] * xv[7][r];
                acc[p][r] = fmaf(cv, u, acc[p][r]);
            }
        }
        buf ^= 1;
    }
#pragma unroll
    for (int p = 0; p < PP_; ++p) {
        float4 o4 = make_float4(acc[p][0], acc[p][1], acc[p][2], acc[p][3]);
        *(float4*)&partial[(size_t)(seg * PAIRS_ + p0 + p) * B_ + b0] = o4;   // coalesced
    }
}

// Stage 1: sum 32 segs per block -> part2[sc][pair][b]. Fully coalesced.
__global__ __launch_bounds__(256) void red1_kernel(const float* __restrict__ partial,
                                                   float* __restrict__ part2)
{
    int pair = blockIdx.x;
    int sc   = blockIdx.y;
    int b    = threadIdx.x;
    float s = 0.f;
    for (int k = 0; k < SEGS_ / SC_; ++k) {
        int seg = sc * (SEGS_ / SC_) + k;
        s += partial[(size_t)(seg * PAIRS_ + pair) * B_ + b];
    }
    part2[((size_t)sc * PAIRS_ + pair) * B_ + b] = s;
}

// Stage 2: finish sum over 4 chunks, squash over o, write vbuf[pair][b] (+ out).
__global__ __launch_bounds__(256) void red2_kernel(const float* __restrict__ part2,
                                                   float* __restrict__ vbuf,
                                                   float* __restrict__ out,
                                                   int write_out)
{
    int j    = blockIdx.x;
    int bq   = blockIdx.y;                 // 0..3
    int lane = threadIdx.x & 63;
    int og   = threadIdx.x >> 6;           // 0..3
    int b    = bq * 64 + lane;
    __shared__ float so[DO_][64];
#pragma unroll
    for (int oo = 0; oo < 4; ++oo) {
        int o = og * 4 + oo;
        int pair = j * DO_ + o;
        float s = part2[((size_t)0 * PAIRS_ + pair) * B_ + b]
                + part2[((size_t)1 * PAIRS_ + pair) * B_ + b]
                + part2[((size_t)2 * PAIRS_ + pair) * B_ + b]
                + part2[((size_t)3 * PAIRS_ + pair) * B_ + b];
        so[o][lane] = s;
    }
    __syncthreads();
    float sq = 0.f;
#pragma unroll
    for (int o = 0; o < DO_; ++o) sq += so[o][lane] * so[o][lane];
    float f = (sq / (1.f + sq)) * rsqrtf(sq + 1e-9f);
#pragma unroll
    for (int oo = 0; oo < 4; ++oo) {
        int o = og * 4 + oo;
        float vv = so[o][lane] * f;
        vbuf[(j * DO_ + o) * B_ + b] = vv;
        if (write_out) out[(size_t)b * PAIRS_ + j * DO_ + o] = vv;
    }
}

// Block per i (all j local) -> agreement update AND next-iter softmax fused.
// Wave w handles j = w, w+4, w+8. Lanes = b (float4). W s_load, xT/vbuf coalesced.
__global__ __launch_bounds__(256) void agree_kernel(const float* __restrict__ xT,
                                                    const float* __restrict__ W,
                                                    const float* __restrict__ vbuf,
                                                    float* __restrict__ blog,
                                                    float* __restrict__ cmat)
{
    int i    = blockIdx.x;
    int lane = threadIdx.x & 63;
    int wv   = __builtin_amdgcn_readfirstlane(threadIdx.x >> 6);
    int b0   = lane * 4;

    float xv[DI_][4];
#pragma unroll
    for (int d = 0; d < DI_; ++d) {
        float4 t4 = *(const float4*)&xT[(i * DI_ + d) * B_ + b0];
        xv[d][0] = t4.x; xv[d][1] = t4.y; xv[d][2] = t4.z; xv[d][3] = t4.w;
    }
    __shared__ float js[NO_];
    __shared__ float nbs[NO_];
    for (int j = wv; j < NO_; j += 4) {                   // uniform per wave
        const float* __restrict__ wj = W + (size_t)(i * NO_ + j) * DO_ * DI_;
        float aj = 0.f;
#pragma unroll
        for (int o = 0; o < DO_; ++o) {
            const float* wr = wj + o * DI_;                               // s_load x8
            float4 vv = *(const float4*)&vbuf[(j * DO_ + o) * B_ + b0];   // coalesced
            float u0 = wr[0]*xv[0][0] + wr[1]*xv[1][0] + wr[2]*xv[2][0] + wr[3]*xv[3][0]
                     + wr[4]*xv[4][0] + wr[5]*xv[5][0] + wr[6]*xv[6][0] + wr[7]*xv[7][0];
            float u1 = wr[0]*xv[0][1] + wr[1]*xv[1][1] + wr[2]*xv[2][1] + wr[3]*xv[3][1]
                     + wr[4]*xv[4][1] + wr[5]*xv[5][1] + wr[6]*xv[6][1] + wr[7]*xv[7][1];
            float u2 = wr[0]*xv[0][2] + wr[1]*xv[1][2] + wr[2]*xv[2][2] + wr[3]*xv[3][2]
                     + wr[4]*xv[4][2] + wr[5]*xv[5][2] + wr[6]*xv[6][2] + wr[7]*xv[7][2];
            float u3 = wr[0]*xv[0][3] + wr[1]*xv[1][3] + wr[2]*xv[2][3] + wr[3]*xv[3][3]
                     + wr[4]*xv[4][3] + wr[5]*xv[5][3] + wr[6]*xv[6][3] + wr[7]*xv[7][3];
            aj = fmaf(u0, vv.x, aj); aj = fmaf(u1, vv.y, aj);
            aj = fmaf(u2, vv.z, aj); aj = fmaf(u3, vv.w, aj);
        }
        for (int off = 32; off > 0; off >>= 1) aj += __shfl_down(aj, off);
        if (lane == 0) js[j] = aj;
    }
    __syncthreads();
    if (threadIdx.x < NO_) {
        int j = threadIdx.x;
        float nb = blog[i * NO_ + j] + js[j] * (1.f / B_);
        blog[i * NO_ + j] = nb;
        nbs[j] = nb;
    }
    __syncthreads();
    if (threadIdx.x < NO_) {
        int j = threadIdx.x;
        float m = nbs[0];
#pragma unroll
        for (int k = 1; k < NO_; ++k) m = fmaxf(m, nbs[k]);
        float ssum = 0.f;
#pragma unroll
        for (int k = 0; k < NO_; ++k) ssum += __expf(nbs[k] - m);
        cmat[i * NO_ + j] = __expf(nbs[j] - m) / ssum;
    }
}

// ===================== fallback path (proven R4 kernels, small ws) =====================

__global__ __launch_bounds__(256) void c_old(float* __restrict__ blog,
                                             float* __restrict__ cmat, int init)
{
    int i = blockIdx.x * 256 + threadIdx.x;
    if (i >= NI_) return;
    if (init) {
#pragma unroll
        for (int j = 0; j < NO_; ++j) { cmat[i * NO_ + j] = 0.1f; blog[i * NO_ + j] = 0.f; }
        return;
    }
    float r[NO_];
    float m = -1e30f;
#pragma unroll
    for (int j = 0; j < NO_; ++j) { r[j] = blog[i * NO_ + j]; m = fmaxf(m, r[j]); }
    float s = 0.f;
#pragma unroll
    for (int j = 0; j < NO_; ++j) { r[j] = __expf(r[j] - m); s += r[j]; }
    float inv = 1.f / s;
#pragma unroll
    for (int j = 0; j < NO_; ++j) cmat[i * NO_ + j] = r[j] * inv;
}

__global__ __launch_bounds__(640) void sv_old(const float* __restrict__ x,
                                              const float* __restrict__ W,
                                              const float* __restrict__ cmat,
                                              float* __restrict__ vbuf,
                                              float* __restrict__ out,
                                              int write_out)
{
    __shared__ __align__(16) float xL[NI_ * DI_];
    __shared__ float sred[4 * PAIRS_];
    __shared__ float sfin[PAIRS_];
    int b = blockIdx.x;
    {
        const float4* xs = (const float4*)(x + (size_t)b * NI_ * DI_);
        for (int t = threadIdx.x; t < NI_ * DI_ / 4; t += 640) {
            float4 v4 = xs[t];
            int f = 4 * t;
            int d = f / NI_;
            int i = f - d * NI_;
            xL[i * DI_ + d] = v4.x; xL[(i+1) * DI_ + d] = v4.y;
            xL[(i+2) * DI_ + d] = v4.z; xL[(i+3) * DI_ + d] = v4.w;
        }
    }
    __syncthreads();
    int pair = threadIdx.x % PAIRS_;
    int seg  = threadIdx.x / PAIRS_;
    int j    = pair >> 4;
    const float4* Wq = (const float4*)W;
    float acc = 0.f;
    int i0 = seg * (NI_ / 4);
    for (int i = i0; i < i0 + NI_ / 4; ++i) {
        float4 w0 = Wq[(i * PAIRS_ + pair) * 2];
        float4 w1 = Wq[(i * PAIRS_ + pair) * 2 + 1];
        const float* xp = &xL[i * DI_];
        float u = w0.x * xp[0] + w0.y * xp[1] + w0.z * xp[2] + w0.w * xp[3]
                + w1.x * xp[4] + w1.y * xp[5] + w1.z * xp[6] + w1.w * xp[7];
        acc = fmaf(cmat[i * NO_ + j], u, acc);
    }
    sred[threadIdx.x] = acc;
    __syncthreads();
    float s = 0.f;
    if (threadIdx.x < PAIRS_) {
        s = sred[threadIdx.x] + sred[PAIRS_ + threadIdx.x]
          + sred[2 * PAIRS_ + threadIdx.x] + sred[3 * PAIRS_ + threadIdx.x];
        sfin[threadIdx.x] = s;
    }
    __syncthreads();
    if (threadIdx.x < PAIRS_) {
        int jj = threadIdx.x >> 4;
        float sq = 0.f;
#pragma unroll
        for (int o = 0; o < DO_; ++o) { float t = sfin[(jj << 4) + o]; sq = fmaf(t, t, sq); }
        float vv = s * (sq / (1.f + sq)) * rsqrtf(sq + 1e-9f);
        vbuf[b * PAIRS_ + threadIdx.x] = vv;
        if (write_out) out[b * PAIRS_ + threadIdx.x] = vv;
    }
}

__global__ __launch_bounds__(256) void agree_old(const float* __restrict__ x,
                                                 const float* __restrict__ W,
                                                 const float* __restrict__ vbuf,
                                                 float* __restrict__ blog)
{
    int i = blockIdx.x;
    int b = threadIdx.x;
    float xr[DI_];
#pragma unroll
    for (int d = 0; d < DI_; ++d) xr[d] = x[((size_t)b * DI_ + d) * NI_ + i];
    __shared__ float red[4][NO_];
    int lane = threadIdx.x & 63;
    int wv   = threadIdx.x >> 6;
    for (int j = 0; j < NO_; ++j) {
        const float* vp = &vbuf[b * PAIRS_ + j * DO_];
        float aj = 0.f;
#pragma unroll
        for (int o = 0; o < DO_; ++o) {
            const float* wr = W + (size_t)((i * NO_ + j) * DO_ + o) * DI_;
            float u = wr[0] * xr[0] + wr[1] * xr[1] + wr[2] * xr[2] + wr[3] * xr[3]
                    + wr[4] * xr[4] + wr[5] * xr[5] + wr[6] * xr[6] + wr[7] * xr[7];
            aj = fmaf(u, vp[o], aj);
        }
        float val = aj;
        for (int off = 32; off > 0; off >>= 1) val += __shfl_down(val, off);
        if (lane == 0) red[wv][j] = val;
    }
    __syncthreads();
    if (threadIdx.x < NO_) {
        float sum = red[0][threadIdx.x] + red[1][threadIdx.x]
                  + red[2][threadIdx.x] + red[3][threadIdx.x];
        blog[i * NO_ + threadIdx.x] += sum * (1.f / B_);
    }
}

// ===================== launch =====================

extern "C" void kernel_launch(void* const* d_in, const int* in_sizes, int n_in,
                              void* d_out, int out_size, void* d_ws, size_t ws_size,
                              hipStream_t stream)
{
    const float* x = (const float*)d_in[0];   // [256,8,1152]
    const float* W = (const float*)d_in[1];   // [1152,10,16,8]
    float* out = (float*)d_out;               // [256,10,16]

    const size_t XT_N  = (size_t)NI_ * DI_ * B_;         // 2,359,296
    const size_t LOG_N = NI_ * NO_;                      // 11,520
    const size_t V_N   = PAIRS_ * B_;                    // 40,960
    const size_t P_N   = (size_t)SEGS_ * PAIRS_ * B_;    // 5,242,880
    const size_t P2_N  = (size_t)SC_ * PAIRS_ * B_;      // 163,840
    const size_t NEED  = (XT_N + 2 * LOG_N + V_N + P_N + P2_N) * sizeof(float); // ~31.3 MB

    if (ws_size >= NEED) {
        float* xT      = (float*)d_ws;
        float* blog    = xT + XT_N;
        float* cmat    = blog + LOG_N;
        float* vbuf    = cmat + LOG_N;
        float* partial = vbuf + V_N;
        float* part2   = partial + P_N;

        prep_kernel<<<(NI_ * DI_ * B_) / 256, 256, 0, stream>>>(x, xT, blog, cmat);
        for (int it = 0; it < 3; ++it) {
            sv_kernel<<<dim3(8, SEGS_), 256, 0, stream>>>(xT, W, cmat, partial);
            red1_kernel<<<dim3(PAIRS_, SC_), 256, 0, stream>>>(partial, part2);
            red2_kernel<<<dim3(NO_, B_ / 64), 256, 0, stream>>>(part2, vbuf, out,
                                                                it == 2 ? 1 : 0);
            if (it < 2) agree_kernel<<<NI_, 256, 0, stream>>>(xT, W, vbuf, blog, cmat);
        }
    } else {
        float* blog = (float*)d_ws;
        float* cmat = blog + LOG_N;
        float* vbuf = cmat + LOG_N;
        for (int it = 0; it < 3; ++it) {
            c_old<<<(NI_ + 255) / 256, 256, 0, stream>>>(blog, cmat, it == 0 ? 1 : 0);
            sv_old<<<B_, 640, 0, stream>>>(x, W, cmat, vbuf, out, it == 2 ? 1 : 0);
            if (it < 2) agree_old<<<NI_, 256, 0, stream>>>(x, W, vbuf, blog);
        }
    }
}